// Round 2
// baseline (123228.271 us; speedup 1.0000x reference)
//
#include <hip/hip_runtime.h>
#include <math.h>

// B=32, T=512, IDIM=512, ODIM=80, L=256, DUNITS=1024, ATT=128, ACH=10, AK=31, PRE=256, POST=512

__device__ __forceinline__ float sigm(float x){ return 1.0f/(1.0f+__expf(-x)); }

// ---------------- workspace layout (floats) ----------------
#define OFF_ENC   0          // 2097152  enc_proj (B,T,ATT)
#define OFF_AW    2097152    // 16384    aw (B,T)
#define OFF_E     2113536    // 16384    e (B,T)
#define OFF_XC    2129920    // 24576    xc interleaved-4: [(k>>2)*128 + b*4 + (k&3)], k<768
#define OFF_Z0T   2154496    // 65536    z0 transposed-i4, 2 parities
#define OFF_Z1T   2220032    // 65536
#define OFF_C0T   2285568    // 32768    c0T[u*32+b]
#define OFF_C1T   2318336    // 32768
#define OFF_DEC   2351104    // 4096     dec_g[b*128+a]
#define OFF_PREV  2355200    // 4096     prev_g[b*128+o]
#define OFF_OUTS  2359296    // 655360   outs_ws (B,80,256)
#define OFF_PN1   3014656    // 4194304
#define OFF_PN2   7208960    // 4194304
#define OFF_BSC   11403264   // 512
#define OFF_BSH   11403776   // 512
#define OFF_BAR   11404288   // 256 uints

// ---------------- init ----------------
__global__ void k_init(float* __restrict__ ws, const int* __restrict__ hlens,
                       const int* __restrict__ ylens, float* __restrict__ d_out) {
  int i = blockIdx.x*256 + threadIdx.x;
  float* z0T = ws + OFF_Z0T;  float* z1T = ws + OFF_Z1T;
  float* c0T = ws + OFF_C0T;  float* c1T = ws + OFF_C1T;
  float* decg = ws + OFF_DEC; float* aw = ws + OFF_AW;
  unsigned* bar = (unsigned*)(ws + OFF_BAR);
  if (i < 65536) {
    z0T[i] = 0.f; z1T[i] = 0.f;
  } else if (i < 98304) {
    int j = i - 65536; c0T[j] = 0.f; c1T[j] = 0.f;
  } else if (i < 102400) {
    decg[i - 98304] = 0.f;
  } else if (i < 102656) {
    bar[i - 102400] = 0u;
  } else if (i < 119040) {
    int j = i - 102656; int b = j >> 9; int t = j & 511;
    int hl = hlens[b];
    aw[j] = (t < hl) ? 1.0f/(float)hl : 0.f;
  } else if (i < 119072) {
    int b = i - 119040;
    d_out[663552 + b] = (float)ylens[b];
  }
}

// ---------------- enc_proj = hs @ w_enc + b_enc ----------------
__global__ void k_encproj(const float* __restrict__ hs, const float* __restrict__ w_enc,
                          const float* __restrict__ b_enc, float* __restrict__ enc_proj) {
  __shared__ float hsl[16*512];
  int b = blockIdx.x, t0 = blockIdx.y*16;
  int tid = threadIdx.x;  // 256
  for (int i = tid; i < 16*512; i += 256)
    hsl[i] = hs[(size_t)(b*512 + t0 + (i>>9))*512 + (i&511)];
  __syncthreads();
  int a = tid & 127, tq = tid >> 7;
  float acc[8];
  #pragma unroll
  for (int u=0;u<8;++u) acc[u]=0.f;
  for (int d=0; d<512; ++d) {
    float w = w_enc[d*128 + a];
    #pragma unroll
    for (int u=0;u<8;++u) acc[u] += hsl[(tq*8+u)*512 + d]*w;
  }
  float be = b_enc[a];
  #pragma unroll
  for (int u=0;u<8;++u)
    enc_proj[(size_t)(b*512 + t0 + tq*8 + u)*128 + a] = acc[u] + be;
}

// ---------------- grid barrier ----------------
__device__ __forceinline__ void gsync(unsigned* bar, unsigned gen) {
  __syncthreads();
  if (threadIdx.x == 0) {
    __threadfence();
    __hip_atomic_fetch_add(&bar[(blockIdx.x & 7) * 32], 1u,
                           __ATOMIC_RELEASE, __HIP_MEMORY_SCOPE_AGENT);
  }
  if (threadIdx.x < 8) {
    unsigned tgt = gen * 32u;
    while (__hip_atomic_load(&bar[threadIdx.x * 32],
                             __ATOMIC_RELAXED, __HIP_MEMORY_SCOPE_AGENT) < tgt) {
      __builtin_amdgcn_s_sleep(1);
    }
  }
  __syncthreads();
  if (threadIdx.x == 0) __threadfence();
  __syncthreads();
}

// ---------------- LSTM phase helper (no intra-phase global deps) ----------------
__device__ __forceinline__ void lstm_phase(
    const float* __restrict__ xin, int xk4, const float* __restrict__ wih, int xK,
    const float* __restrict__ whh, const float* __restrict__ bias,
    const float* __restrict__ hin, float* __restrict__ cT, float* __restrict__ zw,
    float* smem) {
  int tid = threadIdx.x, bid = blockIdx.x;
  int b = tid & 31, jq = tid >> 5;            // jq 0..15
  int gate = jq >> 2, uo = jq & 3;
  int j0 = gate*1024 + bid*4 + uo;
  const float4* wx = (const float4*)(wih + (size_t)j0*xK);
  const float4* wh = (const float4*)(whh + (size_t)j0*1024);
  const float4* x4 = (const float4*)xin;
  const float4* h4 = (const float4*)hin;
  float a0=0.f, a1=0.f, a2=0.f, a3=0.f;
  for (int k4 = 0; k4 < xk4; k4 += 4) {
    float4 w0=wx[k4], w1=wx[k4+1], w2=wx[k4+2], w3=wx[k4+3];
    float4 x0=x4[(k4+0)*32+b], x1=x4[(k4+1)*32+b], x2=x4[(k4+2)*32+b], x3=x4[(k4+3)*32+b];
    a0 += w0.x*x0.x + w0.y*x0.y + w0.z*x0.z + w0.w*x0.w;
    a1 += w1.x*x1.x + w1.y*x1.y + w1.z*x1.z + w1.w*x1.w;
    a2 += w2.x*x2.x + w2.y*x2.y + w2.z*x2.z + w2.w*x2.w;
    a3 += w3.x*x3.x + w3.y*x3.y + w3.z*x3.z + w3.w*x3.w;
  }
  for (int k4 = 0; k4 < 256; k4 += 4) {
    float4 w0=wh[k4], w1=wh[k4+1], w2=wh[k4+2], w3=wh[k4+3];
    float4 x0=h4[(k4+0)*32+b], x1=h4[(k4+1)*32+b], x2=h4[(k4+2)*32+b], x3=h4[(k4+3)*32+b];
    a0 += w0.x*x0.x + w0.y*x0.y + w0.z*x0.z + w0.w*x0.w;
    a1 += w1.x*x1.x + w1.y*x1.y + w1.z*x1.z + w1.w*x1.w;
    a2 += w2.x*x2.x + w2.y*x2.y + w2.z*x2.z + w2.w*x2.w;
    a3 += w3.x*x3.x + w3.y*x3.y + w3.z*x3.z + w3.w*x3.w;
  }
  float g = ((a0+a1)+(a2+a3)) + bias[j0];
  smem[jq*33 + b] = g;
  __syncthreads();
  if (tid < 128) {
    int b2 = tid & 31, uo2 = tid >> 5;
    float gi = smem[(0*4 + uo2)*33 + b2];
    float gf = smem[(1*4 + uo2)*33 + b2];
    float gg = smem[(2*4 + uo2)*33 + b2];
    float go = smem[(3*4 + uo2)*33 + b2];
    int u = bid*4 + uo2;
    float c_old = cT[u*32 + b2];
    float c_new = sigm(gf)*c_old + sigm(gi)*tanhf(gg);
    cT[u*32 + b2] = c_new;
    zw[bid*128 + b2*4 + uo2] = sigm(go)*tanhf(c_new);
  }
}

// ---------------- persistent scan kernel: 256 blocks x 512 threads ----------------
__global__ __launch_bounds__(512, 2) void k_scan(
    const float* __restrict__ hs, const int* __restrict__ hlens,
    const float* __restrict__ loc_k, const float* __restrict__ w_loc,
    const float* __restrict__ gvec, const float* __restrict__ w_dec,
    const float* __restrict__ pre_w1, const float* __restrict__ pre_b1,
    const float* __restrict__ pre_w2, const float* __restrict__ pre_b2,
    const float* __restrict__ l0_wih, const float* __restrict__ l0_whh,
    const float* __restrict__ l0_b, const float* __restrict__ l1_wih,
    const float* __restrict__ l1_whh, const float* __restrict__ l1_b,
    const float* __restrict__ feat_w, const float* __restrict__ feat_b,
    const float* __restrict__ prob_w, const float* __restrict__ prob_b,
    float* __restrict__ ws, float* __restrict__ probs_out) {
  __shared__ float smem[2048];
  int tid = threadIdx.x, bid = blockIdx.x;

  float* enc_proj = ws + OFF_ENC;
  float* aw   = ws + OFF_AW;
  float* e    = ws + OFF_E;
  float* xc   = ws + OFF_XC;
  float* z0T  = ws + OFF_Z0T;
  float* z1T  = ws + OFF_Z1T;
  float* c0T  = ws + OFF_C0T;
  float* c1T  = ws + OFF_C1T;
  float* decg = ws + OFF_DEC;
  float* prevg= ws + OFF_PREV;
  float* outs_ws = ws + OFF_OUTS;
  unsigned* bar = (unsigned*)(ws + OFF_BAR);

  unsigned gen = 0;

  for (int s = 0; s < 256; ++s) {
    int p = s & 1;
    const float* z0r = z0T + p*32768;  float* z0w = z0T + (1-p)*32768;
    const float* z1r = z1T + p*32768;  float* z1w = z1T + (1-p)*32768;

    // ===== Phase A: location conv + energies; tc==0 blocks also out/prob GEMV =====
    {
      int b = bid >> 3, tc = bid & 7, t0 = tc*64;
      int a = tid & 127, th = tid >> 7;    // th 0..3
      int hl_b = hlens[b];
      // smem carve: awin[0..96) loc[96..736) red8[736..864) sred4[864..1376)
      float* s_awin = smem;
      float* s_loc  = smem + 96;
      float* s_red8 = smem + 736;
      float* s_sred = smem + 864;
      if (tid < 94) {
        int idx = t0 - 15 + tid;
        s_awin[tid] = (idx >= 0 && idx < 512) ? aw[b*512 + idx] : 0.f;
      }
      float wl[10];
      #pragma unroll
      for (int c = 0; c < 10; ++c) wl[c] = w_loc[c*128 + a];
      float dec_a = decg[b*128 + a];
      float gv = gvec[a];
      __syncthreads();
      for (int i = tid; i < 640; i += 512) {
        int c = i >> 6, tt = i & 63;
        float s2 = 0.f;
        #pragma unroll
        for (int k = 0; k < 31; ++k) s2 += s_awin[tt + k]*loc_k[c*31 + k];
        s_loc[c*64 + tt] = s2;
      }
      __syncthreads();
      for (int q = 0; q < 16; ++q) {
        int tt = th*16 + q;
        float s2 = enc_proj[(size_t)(b*512 + t0 + tt)*128 + a] + dec_a;
        #pragma unroll
        for (int c = 0; c < 10; ++c) s2 += s_loc[c*64 + tt]*wl[c];
        float v = tanhf(s2)*gv;
        #pragma unroll
        for (int off = 32; off; off >>= 1) v += __shfl_down(v, off);
        if ((tid & 63) == 0) s_red8[(tid >> 6)*16 + q] = v;
      }
      __syncthreads();
      if (tid < 64) {
        int th2 = tid >> 4, q = tid & 15;
        float ee = s_red8[(2*th2)*16 + q] + s_red8[(2*th2+1)*16 + q];
        int t = t0 + tid;
        e[b*512 + t] = (t < hl_b) ? ee : -1e30f;
      }
      if (tc == 0) {
        // out/prob GEMV from z1r (this is "prev" for step s)
        int o = a, ks = th;
        float facc = 0.f;
        const float4* z1r4 = (const float4*)z1r;
        if (o < 81) {
          for (int k4 = ks*64; k4 < ks*64 + 64; ++k4) {
            float4 zv = z1r4[k4*32 + b];
            int k = k4*4;
            if (o < 80) {
              facc += zv.x*feat_w[(k+0)*80+o] + zv.y*feat_w[(k+1)*80+o]
                    + zv.z*feat_w[(k+2)*80+o] + zv.w*feat_w[(k+3)*80+o];
            } else {
              facc += zv.x*prob_w[k+0] + zv.y*prob_w[k+1]
                    + zv.z*prob_w[k+2] + zv.w*prob_w[k+3];
            }
          }
        }
        __syncthreads();
        if (o < 81) s_sred[ks*128 + o] = facc;
        __syncthreads();
        if (tid < 81) {
          float o4 = s_sred[tid] + s_sred[128+tid] + s_sred[256+tid] + s_sred[384+tid];
          if (tid < 80) {
            float ov = o4 + feat_b[tid];
            prevg[b*128 + tid] = ov;
            if (s > 0) outs_ws[(b*80 + tid)*256 + (s-1)] = ov;
          } else {
            if (s > 0) probs_out[b*256 + (s-1)] = o4 + prob_b[0];
          }
        }
      }
    }
    gen++; gsync(bar, gen);

    // ===== Phase B: softmax + context; dc==0 blocks also prenet =====
    {
      int b = bid >> 3, dc = bid & 7;
      float* s_aws  = smem;          // 512
      float* s_red  = smem + 512;    // 8
      float* s_red2 = smem + 520;    // 8
      float* s_cred = smem + 528;    // 512
      float* s_h1   = smem + 1040;   // 256
      float* s_prev = smem + 1296;   // 80
      float ev = e[b*512 + tid];
      float m = ev;
      #pragma unroll
      for (int off = 32; off; off >>= 1) m = fmaxf(m, __shfl_xor(m, off));
      if ((tid & 63) == 0) s_red[tid >> 6] = m;
      __syncthreads();
      m = s_red[0];
      #pragma unroll
      for (int w2 = 1; w2 < 8; ++w2) m = fmaxf(m, s_red[w2]);
      float pexp = __expf(ev - m);
      float ssum = pexp;
      #pragma unroll
      for (int off = 32; off; off >>= 1) ssum += __shfl_xor(ssum, off);
      if ((tid & 63) == 0) s_red2[tid >> 6] = ssum;
      __syncthreads();
      ssum = s_red2[0];
      #pragma unroll
      for (int w2 = 1; w2 < 8; ++w2) ssum += s_red2[w2];
      float awv = pexp / ssum;
      s_aws[tid] = awv;
      if (dc == 0) aw[b*512 + tid] = awv;
      __syncthreads();
      int d = tid & 63, th = tid >> 6;
      int dg = dc*64 + d;
      float cacc = 0.f;
      const float* hp = hs + (size_t)(b*512 + th*64)*512 + dg;
      for (int t = 0; t < 64; ++t) cacc += s_aws[th*64 + t]*hp[(size_t)t*512];
      s_cred[th*64 + d] = cacc;
      __syncthreads();
      if (tid < 64) {
        float v = 0.f;
        #pragma unroll
        for (int w2 = 0; w2 < 8; ++w2) v += s_cred[w2*64 + tid];
        int kk = dc*64 + tid;
        xc[(kk >> 2)*128 + b*4 + (kk & 3)] = v;
      }
      if (dc == 0) {
        if (tid < 80) s_prev[tid] = prevg[b*128 + tid];
        __syncthreads();
        if (tid < 256) {
          float acc1 = pre_b1[tid];
          for (int k = 0; k < 80; ++k) acc1 += s_prev[k]*pre_w1[k*256 + tid];
          s_h1[tid] = fmaxf(acc1, 0.f);
        }
        __syncthreads();
        if (tid < 256) {
          float acc2 = pre_b2[tid];
          for (int k = 0; k < 256; ++k) acc2 += s_h1[k]*pre_w2[k*256 + tid];
          float pv = fmaxf(acc2, 0.f);
          int kk = 512 + tid;
          xc[(kk >> 2)*128 + b*4 + (kk & 3)] = pv;
        }
      }
    }
    gen++; gsync(bar, gen);

    // ===== Phase C: LSTM0 =====
    lstm_phase(xc, 192, l0_wih, 768, l0_whh, l0_b, z0r, c0T, z0w, smem);
    gen++; gsync(bar, gen);

    // ===== Phase D: LSTM1 (+ blocks 0..7 compute dec for next step) =====
    lstm_phase(z0w, 256, l1_wih, 1024, l1_whh, l1_b, z1r, c1T, z1w, smem);
    if (bid < 8) {
      int a4 = tid & 15, b = tid >> 4;        // b 0..31
      int aa = bid*16 + a4;
      const float4* z4 = (const float4*)z0w;
      float acc = 0.f;
      for (int k4 = 0; k4 < 256; ++k4) {
        float4 zv = z4[k4*32 + b];
        int k = k4*4;
        acc += zv.x*w_dec[(k+0)*128 + aa] + zv.y*w_dec[(k+1)*128 + aa]
             + zv.z*w_dec[(k+2)*128 + aa] + zv.w*w_dec[(k+3)*128 + aa];
      }
      decg[b*128 + aa] = acc;
    }
    gen++; gsync(bar, gen);
  }

  // ===== final out/prob (step index 255) from final z1 (parity 0) =====
  if (bid < 32) {
    int b = bid;
    int o = tid & 127, ks = tid >> 7;
    float* s_sred = smem + 864;
    const float4* z1r4 = (const float4*)z1T;  // parity 0 after 256 steps
    float facc = 0.f;
    if (o < 81) {
      for (int k4 = ks*64; k4 < ks*64 + 64; ++k4) {
        float4 zv = z1r4[k4*32 + b];
        int k = k4*4;
        if (o < 80) {
          facc += zv.x*feat_w[(k+0)*80+o] + zv.y*feat_w[(k+1)*80+o]
                + zv.z*feat_w[(k+2)*80+o] + zv.w*feat_w[(k+3)*80+o];
        } else {
          facc += zv.x*prob_w[k+0] + zv.y*prob_w[k+1]
                + zv.z*prob_w[k+2] + zv.w*prob_w[k+3];
        }
      }
    }
    __syncthreads();
    if (o < 81) s_sred[ks*128 + o] = facc;
    __syncthreads();
    if (tid < 81) {
      float o4 = s_sred[tid] + s_sred[128+tid] + s_sred[256+tid] + s_sred[384+tid];
      if (tid < 80) outs_ws[(b*80 + tid)*256 + 255] = o4 + feat_b[tid];
      else probs_out[b*256 + 255] = o4 + prob_b[0];
    }
  }
}

// ---------------- postnet conv1d (k=5, pad=2), optional fused residual+transpose ----------------
__global__ void k_conv(const float* __restrict__ in, const float* __restrict__ wk,
                       int CI, int CO, float* __restrict__ out,
                       const float* __restrict__ resid, float* __restrict__ final_out) {
  int b = blockIdx.x, coT = blockIdx.y, lT = blockIdx.z;
  int l0 = lT*64;
  int tid = threadIdx.x;
  int lq = tid & 15, coq = tid >> 4;
  __shared__ float xs[16*68];
  __shared__ float wt[64*81];
  float acc[4][4];
  #pragma unroll
  for (int m = 0; m < 4; ++m)
    #pragma unroll
    for (int li = 0; li < 4; ++li) acc[m][li] = 0.f;
  int coBase = coT*64 + coq*4;
  for (int cc0 = 0; cc0 < CI; cc0 += 16) {
    __syncthreads();
    for (int i = tid; i < 16*68; i += 256) {
      int ci = i/68, pos = i - ci*68;
      int gl = l0 - 2 + pos;
      xs[i] = (gl >= 0 && gl < 256) ? in[((size_t)b*CI + cc0 + ci)*256 + gl] : 0.f;
    }
    for (int i = tid; i < 64*80; i += 256) {
      int co_i = i/80, rem = i - co_i*80;
      int cog = coT*64 + co_i;
      float w = (cog < CO) ? wk[(size_t)cog*CI*5 + (size_t)cc0*5 + rem] : 0.f;
      wt[co_i*81 + rem] = w;
    }
    __syncthreads();
    #pragma unroll 2
    for (int ci = 0; ci < 16; ++ci) {
      float4 xa = *(const float4*)&xs[ci*68 + lq*4];
      float4 xb = *(const float4*)&xs[ci*68 + lq*4 + 4];
      float x8[8] = {xa.x, xa.y, xa.z, xa.w, xb.x, xb.y, xb.z, xb.w};
      #pragma unroll
      for (int kk = 0; kk < 5; ++kk) {
        float w0 = wt[(coq*4+0)*81 + ci*5 + kk];
        float w1 = wt[(coq*4+1)*81 + ci*5 + kk];
        float w2 = wt[(coq*4+2)*81 + ci*5 + kk];
        float w3 = wt[(coq*4+3)*81 + ci*5 + kk];
        #pragma unroll
        for (int li = 0; li < 4; ++li) {
          float xv = x8[kk + li];
          acc[0][li] += w0*xv; acc[1][li] += w1*xv;
          acc[2][li] += w2*xv; acc[3][li] += w3*xv;
        }
      }
    }
  }
  if (final_out) {
    #pragma unroll
    for (int m = 0; m < 4; ++m) {
      int co = coBase + m;
      if (co < CO) {
        #pragma unroll
        for (int li = 0; li < 4; ++li) {
          int l = l0 + lq*4 + li;
          final_out[(size_t)(b*256 + l)*80 + co] =
              acc[m][li] + resid[((size_t)b*80 + co)*256 + l];
        }
      }
    }
  } else {
    #pragma unroll
    for (int m = 0; m < 4; ++m) {
      int co = coBase + m;
      if (co < CO) {
        float4 v = {acc[m][0], acc[m][1], acc[m][2], acc[m][3]};
        *(float4*)&out[((size_t)b*CO + co)*256 + l0 + lq*4] = v;
      }
    }
  }
}

// ---------------- BN train-mode stats ----------------
__global__ void k_bnstats(const float* __restrict__ x, const float* __restrict__ g,
                          const float* __restrict__ bt, float* __restrict__ scale,
                          float* __restrict__ shift) {
  int c = blockIdx.x;
  int tid = threadIdx.x;  // 256
  float s = 0.f, s2 = 0.f;
  for (int i = tid; i < 8192; i += 256) {
    int bb = i >> 8, l = i & 255;
    float v = x[((size_t)bb*512 + c)*256 + l];
    s += v; s2 += v*v;
  }
  __shared__ float rs[256], rs2[256];
  rs[tid] = s; rs2[tid] = s2;
  __syncthreads();
  for (int st = 128; st; st >>= 1) {
    if (tid < st) { rs[tid] += rs[tid + st]; rs2[tid] += rs2[tid + st]; }
    __syncthreads();
  }
  if (tid == 0) {
    float m = rs[0]/8192.f;
    float var = rs2[0]/8192.f - m*m;
    float inv = rsqrtf(var + 1e-5f);
    float sc = g[c]*inv;
    scale[c] = sc;
    shift[c] = bt[c] - m*sc;
  }
}

__global__ void k_bnapply(float* __restrict__ x, const float* __restrict__ scale,
                          const float* __restrict__ shift) {
  int i = blockIdx.x*256 + threadIdx.x;
  if (i < 32*512*256) {
    int c = (i >> 8) & 511;
    x[i] = tanhf(scale[c]*x[i] + shift[c]);
  }
}

// ---------------- launcher ----------------
extern "C" void kernel_launch(void* const* d_in, const int* in_sizes, int n_in,
                              void* d_out, int out_size, void* d_ws, size_t ws_size,
                              hipStream_t stream) {
  const float* hs       = (const float*)d_in[0];
  const int*   hlens    = (const int*)d_in[1];
  const int*   ylens    = (const int*)d_in[3];
  const float* w_enc    = (const float*)d_in[4];
  const float* b_enc    = (const float*)d_in[5];
  const float* w_dec    = (const float*)d_in[6];
  const float* loc_k    = (const float*)d_in[7];
  const float* w_loc    = (const float*)d_in[8];
  const float* gvec     = (const float*)d_in[9];
  const float* pre_w1   = (const float*)d_in[10];
  const float* pre_b1   = (const float*)d_in[11];
  const float* pre_w2   = (const float*)d_in[12];
  const float* pre_b2   = (const float*)d_in[13];
  const float* l0_wih   = (const float*)d_in[14];
  const float* l0_whh   = (const float*)d_in[15];
  const float* l0_b     = (const float*)d_in[16];
  const float* l1_wih   = (const float*)d_in[17];
  const float* l1_whh   = (const float*)d_in[18];
  const float* l1_b     = (const float*)d_in[19];
  const float* feat_w   = (const float*)d_in[20];
  const float* feat_b   = (const float*)d_in[21];
  const float* prob_w   = (const float*)d_in[22];
  const float* prob_b   = (const float*)d_in[23];
  const float* post_k1  = (const float*)d_in[24];
  const float* post_k2  = (const float*)d_in[25];
  const float* post_k3  = (const float*)d_in[26];
  const float* post_k4  = (const float*)d_in[27];
  const float* post_k5  = (const float*)d_in[28];
  const float* bn_g1 = (const float*)d_in[29]; const float* bn_b1 = (const float*)d_in[30];
  const float* bn_g2 = (const float*)d_in[31]; const float* bn_b2 = (const float*)d_in[32];
  const float* bn_g3 = (const float*)d_in[33]; const float* bn_b3 = (const float*)d_in[34];
  const float* bn_g4 = (const float*)d_in[35]; const float* bn_b4 = (const float*)d_in[36];

  float* ws = (float*)d_ws;
  float* enc_proj = ws + OFF_ENC;
  float* outs_ws  = ws + OFF_OUTS;
  float* pn1      = ws + OFF_PN1;
  float* pn2      = ws + OFF_PN2;
  float* bsc      = ws + OFF_BSC;
  float* bsh      = ws + OFF_BSH;

  float* outp  = (float*)d_out;            // outs (B,L,80)
  float* probp = outp + 655360;            // probs (B,L)

  k_init<<<466, 256, 0, stream>>>(ws, hlens, ylens, outp);
  k_encproj<<<dim3(32, 32), 256, 0, stream>>>(hs, w_enc, b_enc, enc_proj);

  k_scan<<<256, 512, 0, stream>>>(hs, hlens, loc_k, w_loc, gvec, w_dec,
                                  pre_w1, pre_b1, pre_w2, pre_b2,
                                  l0_wih, l0_whh, l0_b, l1_wih, l1_whh, l1_b,
                                  feat_w, feat_b, prob_w, prob_b,
                                  ws, probp);

  // postnet
  k_conv<<<dim3(32, 8, 4), 256, 0, stream>>>(outs_ws, post_k1, 80, 512, pn1, nullptr, nullptr);
  k_bnstats<<<512, 256, 0, stream>>>(pn1, bn_g1, bn_b1, bsc, bsh);
  k_bnapply<<<16384, 256, 0, stream>>>(pn1, bsc, bsh);

  k_conv<<<dim3(32, 8, 4), 256, 0, stream>>>(pn1, post_k2, 512, 512, pn2, nullptr, nullptr);
  k_bnstats<<<512, 256, 0, stream>>>(pn2, bn_g2, bn_b2, bsc, bsh);
  k_bnapply<<<16384, 256, 0, stream>>>(pn2, bsc, bsh);

  k_conv<<<dim3(32, 8, 4), 256, 0, stream>>>(pn2, post_k3, 512, 512, pn1, nullptr, nullptr);
  k_bnstats<<<512, 256, 0, stream>>>(pn1, bn_g3, bn_b3, bsc, bsh);
  k_bnapply<<<16384, 256, 0, stream>>>(pn1, bsc, bsh);

  k_conv<<<dim3(32, 8, 4), 256, 0, stream>>>(pn1, post_k4, 512, 512, pn2, nullptr, nullptr);
  k_bnstats<<<512, 256, 0, stream>>>(pn2, bn_g4, bn_b4, bsc, bsh);
  k_bnapply<<<16384, 256, 0, stream>>>(pn2, bsc, bsh);

  k_conv<<<dim3(32, 2, 4), 256, 0, stream>>>(pn2, post_k5, 512, 80, pn1, outs_ws, outp);
}